// Round 7
// baseline (213.648 us; speedup 1.0000x reference)
//
#include <hip/hip_runtime.h>
#include <math.h>

#define BB 4
#define NN 4096
#define DD 128
#define HS 8             // n slices per batch (512 n each)
#define NIT 8            // 64-n tiles per slice
#define QG 32            // m quad-groups per batch (128 m each; 4 waves x 32)

typedef __attribute__((ext_vector_type(8))) short bf16x8;
typedef __attribute__((ext_vector_type(4))) float f32x4;

__device__ __forceinline__ void mfma_16x16x32_bf16(f32x4& d, bf16x8 a, bf16x8 b) {
  asm volatile("v_mfma_f32_16x16x32_bf16 %0, %1, %2, %0" : "+v"(d) : "v"(a), "v"(b));
}

__device__ __forceinline__ void gload16(const void* g, void* lds) {
  __builtin_amdgcn_global_load_lds(
      (const __attribute__((address_space(1))) void*)g,
      (__attribute__((address_space(3))) void*)lds, 16, 0, 0);
}

__device__ __forceinline__ float vexp2(float x) {  // raw v_exp_f32 = 2^x
  float r; asm("v_exp_f32 %0, %1" : "=v"(r) : "v"(x)); return r;
}

__device__ __forceinline__ unsigned short f2b(float x) {  // RNE f32->bf16
  union { float f; unsigned u; } v; v.f = x;
  unsigned r = v.u + 0x7fffu + ((v.u >> 16) & 1u);
  return (unsigned short)(r >> 16);
}

// ---- kernel 1: cast to bf16 (ft pre-scaled by 0.1*log2e) + fs inv-norms ----
__global__ __launch_bounds__(256) void k_prep(const float* __restrict__ fs,
                                              const float* __restrict__ ft,
                                              unsigned* __restrict__ outb,
                                              float* __restrict__ inv_norm) {
  int w = threadIdx.x >> 6, lane = threadIdx.x & 63;
  int row = blockIdx.x * 4 + w;
  bool is_s = row < BB * NN;
  const float* src = is_s ? fs + (size_t)row * DD
                          : ft + ((size_t)row - BB * NN) * DD;
  float2 v = ((const float2*)src)[lane];
  const float C = 0.14426950408889634f;   // 0.1*log2(e): 2^acc == exp(dot/10)
  float cx = is_s ? v.x : v.x * C;
  float cy = is_s ? v.y : v.y * C;
  outb[(size_t)row * 64 + lane] = ((unsigned)f2b(cy) << 16) | f2b(cx);
  if (is_s) {
    float s = v.x * v.x + v.y * v.y;
#pragma unroll
    for (int off = 32; off > 0; off >>= 1) s += __shfl_xor(s, off);
    if (lane == 0) inv_norm[row] = 1.0f / sqrtf(s);
  }
}

// ---- kernel 2: LDS-staged transposed GEMM C[m][n] + fused epilogue ---------
// Block (b, h, q): 4 waves own 128 m-rows of ft (A-frags in regs, wave w gets
// rows q*128+w*32 ..+31), stream the shared fs slice (512 n) in 8 tiles of 64
// staged via global_load_lds double-buffer, ONE barrier per tile.
// Epilogue: exp col-sums (in-thread tree + 2 shfl-adds) -> LDS scratch (pure
// writes, unique n per tile); argmax over n runs fully in-register via packed
// keys (quantized value | inverse (it,fj) code), one exact cross-lane reduce
// at the end.
__global__ __launch_bounds__(256, 4) void k_main(const unsigned short* __restrict__ fsb,
                                                 const unsigned short* __restrict__ ftb,
                                                 const float* __restrict__ inv_norm,
                                                 float* __restrict__ psum,
                                                 float2* __restrict__ pmax) {
  __shared__ __align__(16) char smem[40960];   // 2x16KB fs dbuf + 8KB psum scratch
  float* psb = (float*)(smem + 32768);         // [4 waves][512 n]

  const int t = threadIdx.x;
  const int w = t >> 6, lane = t & 63;
  const int l15 = lane & 15, g = lane >> 4;
  const int bid = blockIdx.x;
  const int q = bid & 31, h = (bid >> 5) & 7, b = bid >> 8;
  const int m0 = q * 128 + w * 32;

  // staging address (16KB tile = 64 rows x 256B, involution swizzle on 16B col)
  const int srcThr = ((t >> 4) << 8) + (((t & 15) ^ ((t >> 4) & 15)) << 4);
  const int ldsThr = w * 1024;                 // wave-uniform base (+lane*16 by HW)

  // A fragments: ft rows m0..m0+31 (pre-scaled), straight from global, once
  const unsigned short* Ab = ftb + ((size_t)b * NN + m0) * DD;
  bf16x8 af[4][2];
#pragma unroll
  for (int kk = 0; kk < 4; kk++)
#pragma unroll
    for (int mf = 0; mf < 2; mf++)
      af[kk][mf] = *(const bf16x8*)(Ab + (mf * 16 + l15) * DD + kk * 32 + g * 8);

  const char* gB0 = (const char*)(fsb + ((size_t)b * NN + h * 512) * DD);
  const float* invb = inv_norm + (size_t)b * NN + h * 512;

  char* cb = smem;            // compute buffer
  char* nb = smem + 16384;    // prefetch buffer

  // stage tile 0
#pragma unroll
  for (int p = 0; p < 4; p++)
    gload16(gB0 + p * 4096 + srcThr, cb + p * 4096 + ldsThr);

  float bkey[2][4];
#pragma unroll
  for (int mf = 0; mf < 2; mf++)
#pragma unroll
    for (int j = 0; j < 4; j++) bkey[mf][j] = 0.0f;

#pragma unroll
  for (int it = 0; it < NIT; ++it) {
    __syncthreads();          // tile it staged & visible; prev buffer free
    if (it + 1 < NIT) {       // prefetch tile it+1 (in flight across compute)
      const char* gBn = gB0 + (it + 1) * 16384;
#pragma unroll
      for (int p = 0; p < 4; p++)
        gload16(gBn + p * 4096 + srcThr, nb + p * 4096 + ldsThr);
    }
    // MFMA: 32 m x 64 n, K=128
    f32x4 acc[2][4] = {};
#pragma unroll
    for (int kk = 0; kk < 4; kk++) {
      bf16x8 bf[4];
#pragma unroll
      for (int fj = 0; fj < 4; fj++)
        bf[fj] = *(const bf16x8*)(cb + (fj * 16 + l15) * 256 + (((kk * 4 + g) ^ l15) << 4));
#pragma unroll
      for (int mf = 0; mf < 2; mf++)
#pragma unroll
        for (int fj = 0; fj < 4; fj++)
          mfma_16x16x32_bf16(acc[mf][fj], af[kk][mf], bf[fj]);
    }
    // per-tile n-scales
    float svn[4];
#pragma unroll
    for (int fj = 0; fj < 4; fj++) svn[fj] = invb[it * 64 + fj * 16 + l15];

    // exp col-sums over this wave's 32 m (acc = dot*0.1*log2e -> 2^acc)
#pragma unroll
    for (int fj = 0; fj < 4; fj++) {
      float e0 = vexp2(acc[0][fj][0]), e1 = vexp2(acc[0][fj][1]);
      float e2 = vexp2(acc[0][fj][2]), e3 = vexp2(acc[0][fj][3]);
      float e4 = vexp2(acc[1][fj][0]), e5 = vexp2(acc[1][fj][1]);
      float e6 = vexp2(acc[1][fj][2]), e7 = vexp2(acc[1][fj][3]);
      float s = ((e0 + e1) + (e2 + e3)) + ((e4 + e5) + (e6 + e7));
      s += __shfl_xor(s, 16);
      s += __shfl_xor(s, 32);
      if (g == 0) psb[w * 512 + it * 64 + fj * 16 + l15] = s;   // unique n: pure write
    }
    // packed-key running argmax over n (3 VALU/elem: fma, and|or, max)
    const unsigned codebase = (unsigned)((7 - it) << 2);
#pragma unroll
    for (int fj = 0; fj < 4; fj++) {
      const unsigned code = codebase | (unsigned)(3 - fj);   // bigger = earlier n
#pragma unroll
      for (int mf = 0; mf < 2; mf++)
#pragma unroll
        for (int j = 0; j < 4; j++) {
          float v = fmaf(acc[mf][fj][j], svn[fj], 4.0f);     // positive -> uint order
          unsigned kb = (__float_as_uint(v) & 0xFFFFFFE0u) | code;
          bkey[mf][j] = fmaxf(bkey[mf][j], __uint_as_float(kb));
        }
    }
    char* tmp = cb; cb = nb; nb = tmp;
  }
  __syncthreads();   // psb complete block-wide

  // psum write-out: combine 4 waves, coalesced (layout psum[b][q][n])
#pragma unroll
  for (int rr = 0; rr < 2; rr++) {
    int nl = rr * 256 + t;
    float s4 = (psb[nl] + psb[512 + nl]) + (psb[1024 + nl] + psb[1536 + nl]);
    psum[((size_t)(b * QG + q)) * NN + h * 512 + nl] = s4;
  }

  // pmax finalize: exact cross-l15 argmax, once
#pragma unroll
  for (int mf = 0; mf < 2; mf++)
#pragma unroll
    for (int j = 0; j < 4; j++) {
      unsigned bits = __float_as_uint(bkey[mf][j]);
      unsigned code = bits & 31u;
      int itw = 7 - (int)(code >> 2);
      int fjw = 3 - (int)(code & 3u);
      int n = h * 512 + itw * 64 + fjw * 16 + l15;
      float vq = __uint_as_float(bits & 0xFFFFFFE0u);
#pragma unroll
      for (int off = 1; off <= 8; off <<= 1) {
        float ov = __shfl_xor(vq, off);
        int   on = __shfl_xor(n, off);
        if (ov > vq || (ov == vq && on < n)) { vq = ov; n = on; }
      }
      if (l15 == 0) {
        int m = m0 + mf * 16 + g * 4 + j;
        float2 pr; pr.x = vq; pr.y = __int_as_float(n);
        pmax[((size_t)b * NN + m) * HS + h] = pr;
      }
    }
}

// ---- kernel 3: per-row finish: argmax over 8 slices, sum 32 psum, pos dot --
__global__ __launch_bounds__(256) void k_post(const float* __restrict__ fs,
                                              const float* __restrict__ ft,
                                              const float* __restrict__ psum,
                                              const float2* __restrict__ pmax,
                                              float* __restrict__ blockpart) {
  __shared__ float part[4];
  int w = threadIdx.x >> 6, lane = threadIdx.x & 63;
  int row = blockIdx.x * 4 + w;          // flat b*N + p
  int b = row >> 12, pn = row & (NN - 1);
  // argmax over the 8 h-slices
  float v = -INFINITY; int i = 0x7fffffff;
  if (lane < HS) {
    float2 pm = pmax[(size_t)row * HS + lane];
    v = pm.x; i = __float_as_int(pm.y);
  }
#pragma unroll
  for (int off = 1; off <= 4; off <<= 1) {
    float ov = __shfl_xor(v, off);
    int   oi = __shfl_xor(i, off);
    if (ov > v || (ov == v && oi < i)) { v = ov; i = oi; }
  }
  int j = __shfl(i, 0);
  // sum the 32 q-partials of all_exp
  float tot = (lane < QG) ? psum[((size_t)(b * QG + lane)) * NN + pn] : 0.0f;
#pragma unroll
  for (int off = 1; off <= 16; off <<= 1) tot += __shfl_xor(tot, off);
  // fp32 dot of fs[row] with ft[b, j]
  float2 a = ((const float2*)(fs + (size_t)row * DD))[lane];
  float2 c = ((const float2*)(ft + ((size_t)b * NN + j) * DD))[lane];
  float s = a.x * c.x + a.y * c.y;
#pragma unroll
  for (int off = 32; off > 0; off >>= 1) s += __shfl_xor(s, off);
  if (lane == 0) {
    float term = logf(tot) - s * 0.1f;
    part[w] = fminf(term, 92.103403719761827f);   // ratio clip at 1e-40
  }
  __syncthreads();
  if (threadIdx.x == 0)
    blockpart[blockIdx.x] = part[0] + part[1] + part[2] + part[3];
}

// ---- kernel 4: final deterministic reduction ------------------------------
__global__ __launch_bounds__(256) void k_final(const float* __restrict__ blockpart,
                                               float* __restrict__ out) {
  __shared__ float red[256];
  float s = 0.0f;
  for (int i = threadIdx.x; i < (BB * NN) / 4; i += 256) s += blockpart[i];
  red[threadIdx.x] = s;
  __syncthreads();
  for (int st = 128; st > 0; st >>= 1) {
    if (threadIdx.x < st) red[threadIdx.x] += red[threadIdx.x + st];
    __syncthreads();
  }
  if (threadIdx.x == 0) out[0] = red[0] * (1.0f / (BB * NN));
}

extern "C" void kernel_launch(void* const* d_in, const int* in_sizes, int n_in,
                              void* d_out, int out_size, void* d_ws, size_t ws_size,
                              hipStream_t stream) {
  const float* fs = (const float*)d_in[0];
  const float* ft = (const float*)d_in[1];
  float* out = (float*)d_out;

  const size_t NE = (size_t)BB * NN * DD;
  unsigned short* fsb = (unsigned short*)d_ws;                   // 4MB
  unsigned short* ftb = fsb + NE;                                // 4MB
  float*  inv_norm = (float*)(ftb + NE);                         // 64KB
  float*  psum     = inv_norm + (size_t)BB * NN;                 // B*32*N f32 (2MB)
  float2* pmax     = (float2*)(psum + (size_t)BB * QG * NN);     // B*N*8 f32x2 (1MB)
  float*  blockpart = (float*)(pmax + (size_t)BB * NN * HS);     // B*N/4 f32

  k_prep<<<(2 * BB * NN) / 4, 256, 0, stream>>>(fs, ft, (unsigned*)fsb, inv_norm);
  // blocks: b(4) x h(8) x q(32) = 1024
  k_main<<<BB * HS * QG, 256, 0, stream>>>(fsb, ftb, inv_norm, psum, pmax);
  k_post<<<(BB * NN) / 4, 256, 0, stream>>>(fs, ft, psum, pmax, blockpart);
  k_final<<<1, 256, 0, stream>>>(blockpart, out);
}

// Round 8
// 54.407 us; speedup vs baseline: 3.9269x; 3.9269x over previous
//
#include <hip/hip_runtime.h>
#include <math.h>

#define BB 4
#define NN 4096
#define DD 128
#define HS 8             // n slices per batch (512 n each)
#define NIT 8            // 64-n tiles per slice
#define QG 32            // m quad-groups per batch (128 m each; 4 waves x 32)

typedef __attribute__((ext_vector_type(8))) short bf16x8;
typedef __attribute__((ext_vector_type(4))) float f32x4;

__device__ __forceinline__ void mfma_16x16x32_bf16(f32x4& d, bf16x8 a, bf16x8 b) {
  asm volatile("v_mfma_f32_16x16x32_bf16 %0, %1, %2, %0" : "+v"(d) : "v"(a), "v"(b));
}

__device__ __forceinline__ void gload16(const void* g, void* lds) {
  __builtin_amdgcn_global_load_lds(
      (const __attribute__((address_space(1))) void*)g,
      (__attribute__((address_space(3))) void*)lds, 16, 0, 0);
}

__device__ __forceinline__ float vexp2(float x) {  // raw v_exp_f32 = 2^x
  float r; asm("v_exp_f32 %0, %1" : "=v"(r) : "v"(x)); return r;
}

__device__ __forceinline__ unsigned short f2b(float x) {  // RNE f32->bf16
  union { float f; unsigned u; } v; v.f = x;
  unsigned r = v.u + 0x7fffu + ((v.u >> 16) & 1u);
  return (unsigned short)(r >> 16);
}

// ---- kernel 1: cast to bf16 (ft pre-scaled by 0.1*log2e) + fs inv-norms ----
__global__ __launch_bounds__(256) void k_prep(const float* __restrict__ fs,
                                              const float* __restrict__ ft,
                                              unsigned* __restrict__ outb,
                                              float* __restrict__ inv_norm) {
  int w = threadIdx.x >> 6, lane = threadIdx.x & 63;
  int row = blockIdx.x * 4 + w;
  bool is_s = row < BB * NN;
  const float* src = is_s ? fs + (size_t)row * DD
                          : ft + ((size_t)row - BB * NN) * DD;
  float2 v = ((const float2*)src)[lane];
  const float C = 0.14426950408889634f;   // 0.1*log2(e): 2^acc == exp(dot/10)
  float cx = is_s ? v.x : v.x * C;
  float cy = is_s ? v.y : v.y * C;
  outb[(size_t)row * 64 + lane] = ((unsigned)f2b(cy) << 16) | f2b(cx);
  if (is_s) {
    float s = v.x * v.x + v.y * v.y;
#pragma unroll
    for (int off = 32; off > 0; off >>= 1) s += __shfl_xor(s, off);
    if (lane == 0) inv_norm[row] = 1.0f / sqrtf(s);
  }
}

// ---- kernel 2: LDS-staged transposed GEMM C[m][n] + fused epilogue ---------
// Block (b, h, q): 4 waves own 128 m-rows of ft (A-frags in regs), stream the
// shared fs slice (512 n) in 8 tiles of 64 via global_load_lds double-buffer,
// ONE barrier per tile. it-loop is kept rolled (#pragma unroll 1): full unroll
// spilled acc/af to scratch (round 7: 222MB writes, 500MB fetch, 5x slower).
__global__ __launch_bounds__(256, 4) void k_main(const unsigned short* __restrict__ fsb,
                                                 const unsigned short* __restrict__ ftb,
                                                 const float* __restrict__ inv_norm,
                                                 float* __restrict__ psum,
                                                 float2* __restrict__ pmax) {
  __shared__ __align__(16) char smem[40960];   // 2x16KB fs dbuf + 8KB psum scratch
  float* psb = (float*)(smem + 32768);         // [4 waves][512 n]

  const int t = threadIdx.x;
  const int w = t >> 6, lane = t & 63;
  const int l15 = lane & 15, g = lane >> 4;
  const int bid = blockIdx.x;
  const int q = bid & 31, h = (bid >> 5) & 7, b = bid >> 8;
  const int m0 = q * 128 + w * 32;

  // staging address (16KB tile = 64 rows x 256B, involution swizzle on 16B col)
  const int srcThr = ((t >> 4) << 8) + (((t & 15) ^ ((t >> 4) & 15)) << 4);
  const int ldsThr = w * 1024;                 // wave-uniform base (+lane*16 by HW)

  // A fragments: ft rows m0..m0+31 (pre-scaled), straight from global, once
  const unsigned short* Ab = ftb + ((size_t)b * NN + m0) * DD;
  bf16x8 af[4][2];
#pragma unroll
  for (int kk = 0; kk < 4; kk++)
#pragma unroll
    for (int mf = 0; mf < 2; mf++)
      af[kk][mf] = *(const bf16x8*)(Ab + (mf * 16 + l15) * DD + kk * 32 + g * 8);

  const char* gB0 = (const char*)(fsb + ((size_t)b * NN + h * 512) * DD);
  const float* invb = inv_norm + (size_t)b * NN + h * 512;

  char* cb = smem;            // compute buffer
  char* nb = smem + 16384;    // prefetch buffer

  // stage tile 0
#pragma unroll
  for (int p = 0; p < 4; p++)
    gload16(gB0 + p * 4096 + srcThr, cb + p * 4096 + ldsThr);

  float bkey[2][4];
#pragma unroll
  for (int mf = 0; mf < 2; mf++)
#pragma unroll
    for (int j = 0; j < 4; j++) bkey[mf][j] = 0.0f;

#pragma unroll 1
  for (int it = 0; it < NIT; ++it) {
    __syncthreads();          // tile it staged & visible; prev buffer free
    if (it + 1 < NIT) {       // prefetch tile it+1 (in flight across compute)
      const char* gBn = gB0 + (it + 1) * 16384;
#pragma unroll
      for (int p = 0; p < 4; p++)
        gload16(gBn + p * 4096 + srcThr, nb + p * 4096 + ldsThr);
    }
    // per-tile n-scales (issue early; consumed after MFMA)
    float svn[4];
#pragma unroll
    for (int fj = 0; fj < 4; fj++) svn[fj] = invb[it * 64 + fj * 16 + l15];

    // MFMA: 32 m x 64 n, K=128
    f32x4 acc[2][4] = {};
#pragma unroll
    for (int kk = 0; kk < 4; kk++) {
      bf16x8 bf[4];
#pragma unroll
      for (int fj = 0; fj < 4; fj++)
        bf[fj] = *(const bf16x8*)(cb + (fj * 16 + l15) * 256 + (((kk * 4 + g) ^ l15) << 4));
#pragma unroll
      for (int mf = 0; mf < 2; mf++)
#pragma unroll
        for (int fj = 0; fj < 4; fj++)
          mfma_16x16x32_bf16(acc[mf][fj], af[kk][mf], bf[fj]);
    }

    // exp col-sums over this wave's 32 m (acc = dot*0.1*log2e -> 2^acc)
#pragma unroll
    for (int fj = 0; fj < 4; fj++) {
      float e0 = vexp2(acc[0][fj][0]), e1 = vexp2(acc[0][fj][1]);
      float e2 = vexp2(acc[0][fj][2]), e3 = vexp2(acc[0][fj][3]);
      float e4 = vexp2(acc[1][fj][0]), e5 = vexp2(acc[1][fj][1]);
      float e6 = vexp2(acc[1][fj][2]), e7 = vexp2(acc[1][fj][3]);
      float s = ((e0 + e1) + (e2 + e3)) + ((e4 + e5) + (e6 + e7));
      s += __shfl_xor(s, 16);
      s += __shfl_xor(s, 32);
      if (g == 0) psb[w * 512 + it * 64 + fj * 16 + l15] = s;   // unique n: pure write
    }
    // packed-key running argmax over n (3 VALU/elem: fma, and|or, max)
    const unsigned codebase = (unsigned)((7 - it) << 2);
#pragma unroll
    for (int fj = 0; fj < 4; fj++) {
      const unsigned code = codebase | (unsigned)(3 - fj);   // bigger = earlier n
#pragma unroll
      for (int mf = 0; mf < 2; mf++)
#pragma unroll
        for (int j = 0; j < 4; j++) {
          float v = fmaf(acc[mf][fj][j], svn[fj], 4.0f);     // positive -> uint order
          unsigned kb = (__float_as_uint(v) & 0xFFFFFFE0u) | code;
          bkey[mf][j] = fmaxf(bkey[mf][j], __uint_as_float(kb));
        }
    }
    char* tmp = cb; cb = nb; nb = tmp;
  }
  __syncthreads();   // psb complete block-wide

  // psum write-out: combine 4 waves, coalesced (layout psum[b][q][n])
#pragma unroll
  for (int rr = 0; rr < 2; rr++) {
    int nl = rr * 256 + t;
    float s4 = (psb[nl] + psb[512 + nl]) + (psb[1024 + nl] + psb[1536 + nl]);
    psum[((size_t)(b * QG + q)) * NN + h * 512 + nl] = s4;
  }

  // pmax finalize: exact cross-l15 argmax, once
#pragma unroll
  for (int mf = 0; mf < 2; mf++)
#pragma unroll
    for (int j = 0; j < 4; j++) {
      unsigned bits = __float_as_uint(bkey[mf][j]);
      unsigned code = bits & 31u;
      int itw = 7 - (int)(code >> 2);
      int fjw = 3 - (int)(code & 3u);
      int n = h * 512 + itw * 64 + fjw * 16 + l15;
      float vq = __uint_as_float(bits & 0xFFFFFFE0u);
#pragma unroll
      for (int off = 1; off <= 8; off <<= 1) {
        float ov = __shfl_xor(vq, off);
        int   on = __shfl_xor(n, off);
        if (ov > vq || (ov == vq && on < n)) { vq = ov; n = on; }
      }
      if (l15 == 0) {
        int m = m0 + mf * 16 + g * 4 + j;
        float2 pr; pr.x = vq; pr.y = __int_as_float(n);
        pmax[((size_t)b * NN + m) * HS + h] = pr;
      }
    }
}

// ---- kernel 3: per-row finish: argmax over 8 slices, sum 32 psum, pos dot --
__global__ __launch_bounds__(256) void k_post(const float* __restrict__ fs,
                                              const float* __restrict__ ft,
                                              const float* __restrict__ psum,
                                              const float2* __restrict__ pmax,
                                              float* __restrict__ blockpart) {
  __shared__ float part[4];
  int w = threadIdx.x >> 6, lane = threadIdx.x & 63;
  int row = blockIdx.x * 4 + w;          // flat b*N + p
  int b = row >> 12, pn = row & (NN - 1);
  // argmax over the 8 h-slices
  float v = -INFINITY; int i = 0x7fffffff;
  if (lane < HS) {
    float2 pm = pmax[(size_t)row * HS + lane];
    v = pm.x; i = __float_as_int(pm.y);
  }
#pragma unroll
  for (int off = 1; off <= 4; off <<= 1) {
    float ov = __shfl_xor(v, off);
    int   oi = __shfl_xor(i, off);
    if (ov > v || (ov == v && oi < i)) { v = ov; i = oi; }
  }
  int j = __shfl(i, 0);
  // sum the 32 q-partials of all_exp
  float tot = (lane < QG) ? psum[((size_t)(b * QG + lane)) * NN + pn] : 0.0f;
#pragma unroll
  for (int off = 1; off <= 16; off <<= 1) tot += __shfl_xor(tot, off);
  // fp32 dot of fs[row] with ft[b, j]
  float2 a = ((const float2*)(fs + (size_t)row * DD))[lane];
  float2 c = ((const float2*)(ft + ((size_t)b * NN + j) * DD))[lane];
  float s = a.x * c.x + a.y * c.y;
#pragma unroll
  for (int off = 32; off > 0; off >>= 1) s += __shfl_xor(s, off);
  if (lane == 0) {
    float term = logf(tot) - s * 0.1f;
    part[w] = fminf(term, 92.103403719761827f);   // ratio clip at 1e-40
  }
  __syncthreads();
  if (threadIdx.x == 0)
    blockpart[blockIdx.x] = part[0] + part[1] + part[2] + part[3];
}

// ---- kernel 4: final deterministic reduction ------------------------------
__global__ __launch_bounds__(256) void k_final(const float* __restrict__ blockpart,
                                               float* __restrict__ out) {
  __shared__ float red[256];
  float s = 0.0f;
  for (int i = threadIdx.x; i < (BB * NN) / 4; i += 256) s += blockpart[i];
  red[threadIdx.x] = s;
  __syncthreads();
  for (int st = 128; st > 0; st >>= 1) {
    if (threadIdx.x < st) red[threadIdx.x] += red[threadIdx.x + st];
    __syncthreads();
  }
  if (threadIdx.x == 0) out[0] = red[0] * (1.0f / (BB * NN));
}

extern "C" void kernel_launch(void* const* d_in, const int* in_sizes, int n_in,
                              void* d_out, int out_size, void* d_ws, size_t ws_size,
                              hipStream_t stream) {
  const float* fs = (const float*)d_in[0];
  const float* ft = (const float*)d_in[1];
  float* out = (float*)d_out;

  const size_t NE = (size_t)BB * NN * DD;
  unsigned short* fsb = (unsigned short*)d_ws;                   // 4MB
  unsigned short* ftb = fsb + NE;                                // 4MB
  float*  inv_norm = (float*)(ftb + NE);                         // 64KB
  float*  psum     = inv_norm + (size_t)BB * NN;                 // B*32*N f32 (2MB)
  float2* pmax     = (float2*)(psum + (size_t)BB * QG * NN);     // B*N*8 f32x2 (1MB)
  float*  blockpart = (float*)(pmax + (size_t)BB * NN * HS);     // B*N/4 f32

  k_prep<<<(2 * BB * NN) / 4, 256, 0, stream>>>(fs, ft, (unsigned*)fsb, inv_norm);
  // blocks: b(4) x h(8) x q(32) = 1024
  k_main<<<BB * HS * QG, 256, 0, stream>>>(fsb, ftb, inv_norm, psum, pmax);
  k_post<<<(BB * NN) / 4, 256, 0, stream>>>(fs, ft, psum, pmax, blockpart);
  k_final<<<1, 256, 0, stream>>>(blockpart, out);
}